// Round 4
// baseline (590.586 us; speedup 1.0000x reference)
//
#include <hip/hip_runtime.h>
#include <hip/hip_bf16.h>

// Problem: B=4, N=4096, D_IN=D_OUT=512, all fp32 in/out.
// out[b,i,:] = (deg_i/r_i) * sum_j g(s_i+s_j)*mask[b,i,j] * y[b,j,:]
//   s = x @ (w@a)  (fp32 exact path)
//   y = x @ w      (bf16 MFMA)
//   g(t) = exp(leaky_0.1(8*tanh(t/8)))
// Workspace layout (bytes):
//   wT16:   0        .. 524288    bf16 w^T [512][512] (k contiguous)
//   v:      524288   .. 526336    fp32 [512]
//   s:      526336   .. 591872    fp32 [16384]
//   x16:    591872   .. 17369088  bf16 x [16384][512]
//   yT:     17369088 .. 34146304  bf16 y^T [512][16384]
// Requires ws_size >= 34146304.

typedef __attribute__((ext_vector_type(4))) float f32x4;
typedef __attribute__((ext_vector_type(8))) short short8;
typedef __attribute__((ext_vector_type(4))) short s16x4;

#define NN 4096
#define DD 512
#define BN_TOT 16384  // B * N

// Raw barrier: waits LDS ops only (lgkmcnt(0)), leaves vmcnt free so global
// prefetches stay in flight across the barrier. __syncthreads() would emit
// s_waitcnt vmcnt(0) and drain them (the round-2 stall).
#define LDS_BARRIER() __asm__ __volatile__("s_waitcnt lgkmcnt(0)\n\ts_barrier" ::: "memory")

__device__ __forceinline__ short f2bf(float f) {
    union { float f; unsigned u; } x;
    x.f = f;
    unsigned r = x.u + 0x7FFFu + ((x.u >> 16) & 1u);  // RTNE
    return (short)(r >> 16);
}

// g(t) = exp(leaky(8*tanh(t/8))); tanh(z) = 1 - 2/(exp(2z)+1); 2z = t/4.
// leaky(c) = max(c, 0.1c) for both signs.
__device__ __forceinline__ float gfun(float t) {
    float e = __expf(t * 0.25f);
    float c = 8.0f - 16.0f * __builtin_amdgcn_rcpf(e + 1.0f);
    c = fmaxf(c, 0.1f * c);
    return __expf(c);
}

// K1a: wT16[d][k] = bf16(w[k][d])
__global__ __launch_bounds__(256) void k_wt(const float* __restrict__ w,
                                            short* __restrict__ wT) {
    int tid = blockIdx.x * 256 + threadIdx.x;  // 0..262143
    int d = tid >> 9, k = tid & 511;
    wT[tid] = f2bf(w[(size_t)k * 512 + d]);
}

// K1b: v[i] = sum_j w[i][j]*a[j]; one wave per i (512 waves)
__global__ __launch_bounds__(256) void k_v(const float* __restrict__ w,
                                           const float* __restrict__ a,
                                           float* __restrict__ v) {
    int gw = (blockIdx.x * 256 + threadIdx.x) >> 6;  // 0..511
    int l = threadIdx.x & 63;
    const float* row = w + (size_t)gw * 512 + l * 8;
    const float* ap = a + l * 8;
    f32x4 w0 = *(const f32x4*)(row);
    f32x4 w1 = *(const f32x4*)(row + 4);
    f32x4 a0 = *(const f32x4*)(ap);
    f32x4 a1 = *(const f32x4*)(ap + 4);
    float p = w0.x * a0.x + w0.y * a0.y + w0.z * a0.z + w0.w * a0.w +
              w1.x * a1.x + w1.y * a1.y + w1.z * a1.z + w1.w * a1.w;
#pragma unroll
    for (int off = 32; off > 0; off >>= 1) p += __shfl_down(p, off);
    if (l == 0) v[gw] = p;
}

// K2: s[row] = x[row]·v ; x16[row] = bf16(x[row]). One wave per row.
__global__ __launch_bounds__(256) void k_s_x16(const float* __restrict__ x,
                                               const float* __restrict__ v,
                                               float* __restrict__ s,
                                               short* __restrict__ x16) {
    __shared__ float vs[512];
    int t = threadIdx.x;
    vs[t] = v[t];
    vs[t + 256] = v[t + 256];
    __syncthreads();
    int w = t >> 6, l = t & 63;
    size_t row = (size_t)blockIdx.x * 4 + w;
    const float* xr = x + row * 512 + l * 8;
    f32x4 x0 = *(const f32x4*)(xr);
    f32x4 x1 = *(const f32x4*)(xr + 4);
    const float* vp = vs + l * 8;
    float p = x0.x * vp[0] + x0.y * vp[1] + x0.z * vp[2] + x0.w * vp[3] +
              x1.x * vp[4] + x1.y * vp[5] + x1.z * vp[6] + x1.w * vp[7];
    short8 pk;
    pk[0] = f2bf(x0.x); pk[1] = f2bf(x0.y); pk[2] = f2bf(x0.z); pk[3] = f2bf(x0.w);
    pk[4] = f2bf(x1.x); pk[5] = f2bf(x1.y); pk[6] = f2bf(x1.z); pk[7] = f2bf(x1.w);
    *(short8*)(x16 + row * 512 + l * 8) = pk;
#pragma unroll
    for (int off = 32; off > 0; off >>= 1) p += __shfl_down(p, off);
    if (l == 0) s[row] = p;
}

// K3: yT[d][bn] = sum_k wT16[d][k] * x16[bn][k]. GEMM-BT, 128x128 tile, BK=64.
// Raw lgkm-only barriers; next-kk global loads stay in flight across them.
__global__ __launch_bounds__(256, 2) void k_ygemm(const short* __restrict__ wT,
                                                  const short* __restrict__ x16,
                                                  short* __restrict__ yT) {
    __shared__ __align__(16) short At[128 * 72];
    __shared__ __align__(16) short Bt[128 * 72];
    const int t = threadIdx.x;
    const int w = t >> 6, l = t & 63;
    const int mt = blockIdx.x & 3, nt = blockIdx.x >> 2;
    const int wr = w >> 1, wc = w & 1;
    f32x4 acc[4][4];
#pragma unroll
    for (int i = 0; i < 4; ++i)
#pragma unroll
        for (int j = 0; j < 4; ++j) acc[i][j] = (f32x4){0.f, 0.f, 0.f, 0.f};

    const short* Ag = wT + (size_t)(mt * 128 + (t >> 3)) * 512 + (t & 7) * 8;
    const short* Bg = x16 + (size_t)(nt * 128 + (t >> 3)) * 512 + (t & 7) * 8;
    short* Aw = At + (t >> 3) * 72 + (t & 7) * 8;
    short* Bw = Bt + (t >> 3) * 72 + (t & 7) * 8;
    const short* Ar = At + (wr * 64 + (l & 15)) * 72 + (l >> 4) * 8;
    const short* Br = Bt + (wc * 64 + (l & 15)) * 72 + (l >> 4) * 8;

    short8 va[4], vb[4];
#pragma unroll
    for (int ii = 0; ii < 4; ++ii) {
        va[ii] = *(const short8*)(Ag + (size_t)ii * 32 * 512);
        vb[ii] = *(const short8*)(Bg + (size_t)ii * 32 * 512);
    }

    for (int kk = 0; kk < 8; ++kk) {
        LDS_BARRIER();  // prior frag reads drained (lgkm only)
#pragma unroll
        for (int ii = 0; ii < 4; ++ii) {
            *(short8*)(Aw + ii * 32 * 72) = va[ii];
            *(short8*)(Bw + ii * 32 * 72) = vb[ii];
        }
        LDS_BARRIER();
        if (kk < 7) {
            const int k0 = (kk + 1) * 64;
#pragma unroll
            for (int ii = 0; ii < 4; ++ii) {
                va[ii] = *(const short8*)(Ag + (size_t)ii * 32 * 512 + k0);
                vb[ii] = *(const short8*)(Bg + (size_t)ii * 32 * 512 + k0);
            }
        }
#pragma unroll
        for (int ks = 0; ks < 2; ++ks) {
            short8 af[4], bfr[4];
#pragma unroll
            for (int it = 0; it < 4; ++it)
                af[it] = *(const short8*)(Ar + it * 16 * 72 + ks * 32);
#pragma unroll
            for (int jt = 0; jt < 4; ++jt)
                bfr[jt] = *(const short8*)(Br + jt * 16 * 72 + ks * 32);
#pragma unroll
            for (int it = 0; it < 4; ++it)
#pragma unroll
                for (int jt = 0; jt < 4; ++jt)
                    acc[it][jt] = __builtin_amdgcn_mfma_f32_16x16x32_bf16(
                        af[it], bfr[jt], acc[it][jt], 0, 0, 0);
        }
    }
    // C/D layout: col = lane&15, row = (lane>>4)*4 + reg
#pragma unroll
    for (int it = 0; it < 4; ++it)
#pragma unroll
        for (int jt = 0; jt < 4; ++jt)
#pragma unroll
            for (int r = 0; r < 4; ++r) {
                int drow = mt * 128 + wr * 64 + it * 16 + (l >> 4) * 4 + r;
                int bn = nt * 128 + wc * 64 + jt * 16 + (l & 15);
                yT[(size_t)drow * BN_TOT + bn] = f2bf(acc[it][jt][r]);
            }
}

// K4: fused mask pass. 512 threads = 8 waves; wave w owns d-slice [w*64,+64).
// grid 512; XCD swizzle: b = (bx&7)>>1 so each XCD's L2 holds one b's 4MB yT
// slice. Per j-tile(64): thread (i=t>>4, seg=t&15) makes 4 P elems; P 32x64
// bf16 double-buffered in LDS; ONE lgkm-only barrier per iter (global loads
// stay in flight); mask loads non-temporal (read-once, don't evict yT).
__global__ __launch_bounds__(512, 4) void k_fused(const float* __restrict__ mask,
                                                  const float* __restrict__ s,
                                                  const short* __restrict__ yT,
                                                  float* __restrict__ out) {
    __shared__ __align__(16) short P[2][32 * 72];
    __shared__ float scl[32];
    const int t = threadIdx.x;
    const int w = t >> 6, l = t & 63;
    const int bx = blockIdx.x;
    const int b = (bx & 7) >> 1;
    const int u = ((bx >> 3) << 1) | (bx & 1);  // 0..127
    const int i0 = u << 5;
    const int i = t >> 4;    // 0..31
    const int seg = t & 15;  // 0..15
    const float s_i = s[b * NN + i0 + i];
    const float* mrow = mask + (size_t)(b * NN + i0 + i) * NN + seg * 4;
    const float* sb = s + b * NN + seg * 4;
    const int d0 = w * 64;
    const short* ybase = yT + (size_t)(d0 + (l & 15)) * BN_TOT + b * NN + ((l >> 4) * 8);
    const int pwoff = i * 72 + seg * 4;
    const int proff = (l & 15) * 72 + (l >> 4) * 8;

    f32x4 acc[2][4];  // [it][dt]
#pragma unroll
    for (int a1 = 0; a1 < 2; ++a1)
#pragma unroll
        for (int a2 = 0; a2 < 4; ++a2) acc[a1][a2] = (f32x4){0.f, 0.f, 0.f, 0.f};
    float r_part = 0.f, deg_part = 0.f;

    // prefetch iter 0 mask/s (nontemporal needs native vector type, not
    // HIP_vector_type struct -> use f32x4)
    f32x4 m0 = __builtin_nontemporal_load((const f32x4*)(mrow));
    f32x4 sj = *(const f32x4*)(sb);

    for (int jt = 0; jt < 64; ++jt) {
        const int buf = jt & 1;
        float mv[4] = {m0.x, m0.y, m0.z, m0.w};
        float sv[4] = {sj.x, sj.y, sj.z, sj.w};

        // batch-issue all 8 B-frag loads for THIS iter (independent of LDS)
        short8 bfr[8];
        const short* yb = ybase + jt * 64;
#pragma unroll
        for (int ks = 0; ks < 2; ++ks)
#pragma unroll
            for (int dt = 0; dt < 4; ++dt)
                bfr[ks * 4 + dt] =
                    *(const short8*)(yb + (size_t)dt * 16 * BN_TOT + ks * 32);

        // prefetch mask/s for jt+1 (stays in flight across the raw barrier)
        if (jt < 63) {
            const int j0n = (jt + 1) * 64;
            m0 = __builtin_nontemporal_load((const f32x4*)(mrow + j0n));
            sj = *(const f32x4*)(sb + j0n);
        }

        // gfun + P write (overlaps in-flight global loads)
        s16x4 pk;
#pragma unroll
        for (int e = 0; e < 4; ++e) {
            float p = gfun(s_i + sv[e]) * mv[e];
            deg_part += mv[e];
            r_part += p;
            pk[e] = f2bf(p);
        }
        *(s16x4*)(P[buf] + pwoff) = pk;

        LDS_BARRIER();  // lgkm-only: P visible, prev-buf reads drained; vmcnt free

#pragma unroll
        for (int ks = 0; ks < 2; ++ks) {
            short8 a0 = *(const short8*)(P[buf] + proff + ks * 32);
            short8 a1 = *(const short8*)(P[buf] + proff + 16 * 72 + ks * 32);
#pragma unroll
            for (int dt = 0; dt < 4; ++dt) {
                acc[0][dt] = __builtin_amdgcn_mfma_f32_16x16x32_bf16(
                    a0, bfr[ks * 4 + dt], acc[0][dt], 0, 0, 0);
                acc[1][dt] = __builtin_amdgcn_mfma_f32_16x16x32_bf16(
                    a1, bfr[ks * 4 + dt], acc[1][dt], 0, 0, 0);
            }
        }
    }
    // reduce r/deg across the 16 seg-threads of each row (consecutive lanes)
#pragma unroll
    for (int off = 1; off < 16; off <<= 1) {
        r_part += __shfl_xor(r_part, off);
        deg_part += __shfl_xor(deg_part, off);
    }
    if (seg == 0) scl[i] = deg_part / r_part;
    __syncthreads();
    // epilogue: C/D layout col = lane&15 (d), row = (lane>>4)*4 + reg (i)
#pragma unroll
    for (int it = 0; it < 2; ++it)
#pragma unroll
        for (int r = 0; r < 4; ++r) {
            const int row = it * 16 + (l >> 4) * 4 + r;
            const float sc = scl[row];
            float* op = out + (size_t)(b * NN + i0 + row) * 512 + d0 + (l & 15);
#pragma unroll
            for (int dt = 0; dt < 4; ++dt)
                __builtin_nontemporal_store(acc[it][dt][r] * sc, op + dt * 16);
        }
}

extern "C" void kernel_launch(void* const* d_in, const int* in_sizes, int n_in,
                              void* d_out, int out_size, void* d_ws, size_t ws_size,
                              hipStream_t stream) {
    const float* x = (const float*)d_in[0];      // [4,4096,512]
    const float* mask = (const float*)d_in[1];   // [4,4096,4096]
    const float* w = (const float*)d_in[2];      // [512,512]
    const float* a = (const float*)d_in[3];      // [512]
    float* out = (float*)d_out;                  // [4,4096,512]
    char* ws = (char*)d_ws;
    short* wT = (short*)(ws);                    // 524288 B
    float* v = (float*)(ws + 524288);            // 2048 B
    float* s = (float*)(ws + 526336);            // 65536 B
    short* x16 = (short*)(ws + 591872);          // 16777216 B
    short* yT = (short*)(ws + 17369088);         // 16777216 B

    hipLaunchKernelGGL(k_wt, dim3(1024), dim3(256), 0, stream, w, wT);
    hipLaunchKernelGGL(k_v, dim3(128), dim3(256), 0, stream, w, a, v);
    hipLaunchKernelGGL(k_s_x16, dim3(4096), dim3(256), 0, stream, x, v, s, x16);
    hipLaunchKernelGGL(k_ygemm, dim3(512), dim3(256), 0, stream, wT, x16, yT);
    hipLaunchKernelGGL(k_fused, dim3(512), dim3(512), 0, stream, mask, s, yT, out);
}

// Round 5
// 498.080 us; speedup vs baseline: 1.1857x; 1.1857x over previous
//
#include <hip/hip_runtime.h>
#include <hip/hip_bf16.h>

// Problem: B=4, N=4096, D_IN=D_OUT=512, all fp32 in/out.
// out[b,i,:] = (deg_i/r_i) * sum_j g(s_i+s_j)*mask[b,i,j] * y[b,j,:]
//   s = x @ (w@a)  (fp32 exact path)
//   y = x @ w      (bf16 MFMA)
//   g(t) = exp(leaky_0.1(8*tanh(t/8)))
// Workspace layout (bytes):
//   wT16:   0        .. 524288    bf16 w^T [512][512] (k contiguous)
//   v:      524288   .. 526336    fp32 [512]
//   s:      526336   .. 591872    fp32 [16384]
//   x16:    591872   .. 17369088  bf16 x [16384][512]
//   yT:     17369088 .. 34146304  bf16 y^T [512][16384]
// Requires ws_size >= 34146304.

typedef __attribute__((ext_vector_type(4))) float f32x4;
typedef __attribute__((ext_vector_type(8))) short short8;

#define NN 4096
#define DD 512
#define BN_TOT 16384  // B * N

// Raw barrier: waits LDS ops only (lgkmcnt(0)), leaves vmcnt free so global
// prefetches stay in flight across the barrier.
#define LDS_BARRIER() __asm__ __volatile__("s_waitcnt lgkmcnt(0)\n\ts_barrier" ::: "memory")

__device__ __forceinline__ short f2bf(float f) {
    union { float f; unsigned u; } x;
    x.f = f;
    unsigned r = x.u + 0x7FFFu + ((x.u >> 16) & 1u);  // RTNE
    return (short)(r >> 16);
}

// g(t) = exp(leaky(8*tanh(t/8))); tanh(z) = 1 - 2/(exp(2z)+1); 2z = t/4.
__device__ __forceinline__ float gfun(float t) {
    float e = __expf(t * 0.25f);
    float c = 8.0f - 16.0f * __builtin_amdgcn_rcpf(e + 1.0f);
    c = fmaxf(c, 0.1f * c);
    return __expf(c);
}

// K1a: wT16[d][k] = bf16(w[k][d])
__global__ __launch_bounds__(256) void k_wt(const float* __restrict__ w,
                                            short* __restrict__ wT) {
    int tid = blockIdx.x * 256 + threadIdx.x;  // 0..262143
    int d = tid >> 9, k = tid & 511;
    wT[tid] = f2bf(w[(size_t)k * 512 + d]);
}

// K1b: v[i] = sum_j w[i][j]*a[j]; one wave per i (512 waves)
__global__ __launch_bounds__(256) void k_v(const float* __restrict__ w,
                                           const float* __restrict__ a,
                                           float* __restrict__ v) {
    int gw = (blockIdx.x * 256 + threadIdx.x) >> 6;  // 0..511
    int l = threadIdx.x & 63;
    const float* row = w + (size_t)gw * 512 + l * 8;
    const float* ap = a + l * 8;
    f32x4 w0 = *(const f32x4*)(row);
    f32x4 w1 = *(const f32x4*)(row + 4);
    f32x4 a0 = *(const f32x4*)(ap);
    f32x4 a1 = *(const f32x4*)(ap + 4);
    float p = w0.x * a0.x + w0.y * a0.y + w0.z * a0.z + w0.w * a0.w +
              w1.x * a1.x + w1.y * a1.y + w1.z * a1.z + w1.w * a1.w;
#pragma unroll
    for (int off = 32; off > 0; off >>= 1) p += __shfl_down(p, off);
    if (l == 0) v[gw] = p;
}

// K2: s[row] = x[row]·v ; x16[row] = bf16(x[row]). One wave per row.
__global__ __launch_bounds__(256) void k_s_x16(const float* __restrict__ x,
                                               const float* __restrict__ v,
                                               float* __restrict__ s,
                                               short* __restrict__ x16) {
    __shared__ float vs[512];
    int t = threadIdx.x;
    vs[t] = v[t];
    vs[t + 256] = v[t + 256];
    __syncthreads();
    int w = t >> 6, l = t & 63;
    size_t row = (size_t)blockIdx.x * 4 + w;
    const float* xr = x + row * 512 + l * 8;
    f32x4 x0 = *(const f32x4*)(xr);
    f32x4 x1 = *(const f32x4*)(xr + 4);
    const float* vp = vs + l * 8;
    float p = x0.x * vp[0] + x0.y * vp[1] + x0.z * vp[2] + x0.w * vp[3] +
              x1.x * vp[4] + x1.y * vp[5] + x1.z * vp[6] + x1.w * vp[7];
    short8 pk;
    pk[0] = f2bf(x0.x); pk[1] = f2bf(x0.y); pk[2] = f2bf(x0.z); pk[3] = f2bf(x0.w);
    pk[4] = f2bf(x1.x); pk[5] = f2bf(x1.y); pk[6] = f2bf(x1.z); pk[7] = f2bf(x1.w);
    *(short8*)(x16 + row * 512 + l * 8) = pk;
#pragma unroll
    for (int off = 32; off > 0; off >>= 1) p += __shfl_down(p, off);
    if (l == 0) s[row] = p;
}

// K3: yT[d][bn] = sum_k wT16[d][k] * x16[bn][k]. GEMM-BT, 128x128 tile, BK=64.
__global__ __launch_bounds__(256, 2) void k_ygemm(const short* __restrict__ wT,
                                                  const short* __restrict__ x16,
                                                  short* __restrict__ yT) {
    __shared__ __align__(16) short At[128 * 72];
    __shared__ __align__(16) short Bt[128 * 72];
    const int t = threadIdx.x;
    const int w = t >> 6, l = t & 63;
    const int mt = blockIdx.x & 3, nt = blockIdx.x >> 2;
    const int wr = w >> 1, wc = w & 1;
    f32x4 acc[4][4];
#pragma unroll
    for (int i = 0; i < 4; ++i)
#pragma unroll
        for (int j = 0; j < 4; ++j) acc[i][j] = (f32x4){0.f, 0.f, 0.f, 0.f};

    const short* Ag = wT + (size_t)(mt * 128 + (t >> 3)) * 512 + (t & 7) * 8;
    const short* Bg = x16 + (size_t)(nt * 128 + (t >> 3)) * 512 + (t & 7) * 8;
    short* Aw = At + (t >> 3) * 72 + (t & 7) * 8;
    short* Bw = Bt + (t >> 3) * 72 + (t & 7) * 8;
    const short* Ar = At + (wr * 64 + (l & 15)) * 72 + (l >> 4) * 8;
    const short* Br = Bt + (wc * 64 + (l & 15)) * 72 + (l >> 4) * 8;

    short8 va[4], vb[4];
#pragma unroll
    for (int ii = 0; ii < 4; ++ii) {
        va[ii] = *(const short8*)(Ag + (size_t)ii * 32 * 512);
        vb[ii] = *(const short8*)(Bg + (size_t)ii * 32 * 512);
    }

    for (int kk = 0; kk < 8; ++kk) {
        LDS_BARRIER();
#pragma unroll
        for (int ii = 0; ii < 4; ++ii) {
            *(short8*)(Aw + ii * 32 * 72) = va[ii];
            *(short8*)(Bw + ii * 32 * 72) = vb[ii];
        }
        LDS_BARRIER();
        if (kk < 7) {
            const int k0 = (kk + 1) * 64;
#pragma unroll
            for (int ii = 0; ii < 4; ++ii) {
                va[ii] = *(const short8*)(Ag + (size_t)ii * 32 * 512 + k0);
                vb[ii] = *(const short8*)(Bg + (size_t)ii * 32 * 512 + k0);
            }
        }
#pragma unroll
        for (int ks = 0; ks < 2; ++ks) {
            short8 af[4], bfr[4];
#pragma unroll
            for (int it = 0; it < 4; ++it)
                af[it] = *(const short8*)(Ar + it * 16 * 72 + ks * 32);
#pragma unroll
            for (int jt = 0; jt < 4; ++jt)
                bfr[jt] = *(const short8*)(Br + jt * 16 * 72 + ks * 32);
#pragma unroll
            for (int it = 0; it < 4; ++it)
#pragma unroll
                for (int jt = 0; jt < 4; ++jt)
                    acc[it][jt] = __builtin_amdgcn_mfma_f32_16x16x32_bf16(
                        af[it], bfr[jt], acc[it][jt], 0, 0, 0);
        }
    }
#pragma unroll
    for (int it = 0; it < 4; ++it)
#pragma unroll
        for (int jt = 0; jt < 4; ++jt)
#pragma unroll
            for (int r = 0; r < 4; ++r) {
                int drow = mt * 128 + wr * 64 + it * 16 + (l >> 4) * 4 + r;
                int bn = nt * 128 + wc * 64 + jt * 16 + (l & 15);
                yT[(size_t)drow * BN_TOT + bn] = f2bf(acc[it][jt][r]);
            }
}

// K4: fused mask pass, v3. R=64 rows/block, grid 256 (1 block/CU).
// Rationale (R4 post-mortem): yT L2 traffic = nblocks * 4MB; R=32/512blk was
// 2 GB of L2 reads = the real bottleneck. R=64/256blk halves it; XCD swizzle
// b = bx&3 puts ONE batch per XCD so its 4MB yT slice fits that XCD's L2.
// 512 threads = 8 waves; wave w owns d-slice [w*64, +64), all 64 i-rows:
// acc 4x4 f32x4. Per j-tile(64): thread (i=t>>3, seg=t&7) makes 8 P elems;
// P 64x64 bf16 double-buffered (stride 72); one lgkm-only barrier per iter;
// mask nt + prefetch-1-ahead (~1600cyc slack > 900cyc HBM latency).
__global__ __launch_bounds__(512, 2) void k_fused(const float* __restrict__ mask,
                                                  const float* __restrict__ s,
                                                  const short* __restrict__ yT,
                                                  float* __restrict__ out) {
    __shared__ __align__(16) short P[2][64 * 72];
    __shared__ float scl[64];
    const int t = threadIdx.x;
    const int w = t >> 6, l = t & 63;
    const int bx = blockIdx.x;
    const int b = bx & 3;                              // one b per XCD
    const int u = ((bx >> 3) << 1) | ((bx >> 2) & 1);  // 0..63
    const int i0 = u << 6;
    const int i = t >> 3;   // 0..63
    const int seg = t & 7;  // 0..7
    const float s_i = s[b * NN + i0 + i];
    const float* mrow = mask + (size_t)(b * NN + i0 + i) * NN + seg * 8;
    const float* sb = s + b * NN + seg * 8;
    const int d0 = w * 64;
    const short* ybase = yT + (size_t)(d0 + (l & 15)) * BN_TOT + b * NN + ((l >> 4) * 8);
    const int pwoff = i * 72 + seg * 8;
    const int proff = (l & 15) * 72 + (l >> 4) * 8;

    f32x4 acc[4][4];  // [it (i)][dt (d)]
#pragma unroll
    for (int a1 = 0; a1 < 4; ++a1)
#pragma unroll
        for (int a2 = 0; a2 < 4; ++a2) acc[a1][a2] = (f32x4){0.f, 0.f, 0.f, 0.f};
    float r_part = 0.f, deg_part = 0.f;

    // prefetch iter 0 mask/s
    f32x4 m0 = __builtin_nontemporal_load((const f32x4*)(mrow));
    f32x4 m1 = __builtin_nontemporal_load((const f32x4*)(mrow + 4));
    f32x4 s0 = *(const f32x4*)(sb);
    f32x4 s1 = *(const f32x4*)(sb + 4);

    for (int jt = 0; jt < 64; ++jt) {
        const int buf = jt & 1;
        float mv[8] = {m0.x, m0.y, m0.z, m0.w, m1.x, m1.y, m1.z, m1.w};
        float sv[8] = {s0.x, s0.y, s0.z, s0.w, s1.x, s1.y, s1.z, s1.w};

        // batch-issue all 8 B-frag loads for THIS iter (L2-resident yT)
        short8 bfr[8];
        const short* yb = ybase + jt * 64;
#pragma unroll
        for (int ks = 0; ks < 2; ++ks)
#pragma unroll
            for (int dt = 0; dt < 4; ++dt)
                bfr[ks * 4 + dt] =
                    *(const short8*)(yb + (size_t)dt * 16 * BN_TOT + ks * 32);

        // prefetch mask/s for jt+1 (stays in flight across the raw barrier)
        if (jt < 63) {
            const int j0n = (jt + 1) * 64;
            m0 = __builtin_nontemporal_load((const f32x4*)(mrow + j0n));
            m1 = __builtin_nontemporal_load((const f32x4*)(mrow + j0n + 4));
            s0 = *(const f32x4*)(sb + j0n);
            s1 = *(const f32x4*)(sb + j0n + 4);
        }

        // gfun + P write (overlaps in-flight global loads)
        short8 pk;
#pragma unroll
        for (int e = 0; e < 8; ++e) {
            float p = gfun(s_i + sv[e]) * mv[e];
            deg_part += mv[e];
            r_part += p;
            pk[e] = f2bf(p);
        }
        *(short8*)(P[buf] + pwoff) = pk;

        LDS_BARRIER();  // lgkm-only: P visible, prev-buf reads drained; vmcnt free

#pragma unroll
        for (int ks = 0; ks < 2; ++ks) {
            short8 afr[4];
#pragma unroll
            for (int it = 0; it < 4; ++it)
                afr[it] = *(const short8*)(P[buf] + proff + it * 16 * 72 + ks * 32);
#pragma unroll
            for (int it = 0; it < 4; ++it)
#pragma unroll
                for (int dt = 0; dt < 4; ++dt)
                    acc[it][dt] = __builtin_amdgcn_mfma_f32_16x16x32_bf16(
                        afr[it], bfr[ks * 4 + dt], acc[it][dt], 0, 0, 0);
        }
    }
    // reduce r/deg across the 8 seg-threads of each row (consecutive lanes)
#pragma unroll
    for (int off = 1; off < 8; off <<= 1) {
        r_part += __shfl_xor(r_part, off);
        deg_part += __shfl_xor(deg_part, off);
    }
    if (seg == 0) scl[i] = deg_part / r_part;
    __syncthreads();
    // epilogue: C/D layout col = lane&15 (d), row = (lane>>4)*4 + reg (i)
#pragma unroll
    for (int it = 0; it < 4; ++it)
#pragma unroll
        for (int r = 0; r < 4; ++r) {
            const int row = it * 16 + (l >> 4) * 4 + r;
            const float sc = scl[row];
            float* op = out + (size_t)(b * NN + i0 + row) * 512 + d0 + (l & 15);
#pragma unroll
            for (int dt = 0; dt < 4; ++dt)
                __builtin_nontemporal_store(acc[it][dt][r] * sc, op + dt * 16);
        }
}

extern "C" void kernel_launch(void* const* d_in, const int* in_sizes, int n_in,
                              void* d_out, int out_size, void* d_ws, size_t ws_size,
                              hipStream_t stream) {
    const float* x = (const float*)d_in[0];      // [4,4096,512]
    const float* mask = (const float*)d_in[1];   // [4,4096,4096]
    const float* w = (const float*)d_in[2];      // [512,512]
    const float* a = (const float*)d_in[3];      // [512]
    float* out = (float*)d_out;                  // [4,4096,512]
    char* ws = (char*)d_ws;
    short* wT = (short*)(ws);                    // 524288 B
    float* v = (float*)(ws + 524288);            // 2048 B
    float* s = (float*)(ws + 526336);            // 65536 B
    short* x16 = (short*)(ws + 591872);          // 16777216 B
    short* yT = (short*)(ws + 17369088);         // 16777216 B

    hipLaunchKernelGGL(k_wt, dim3(1024), dim3(256), 0, stream, w, wT);
    hipLaunchKernelGGL(k_v, dim3(128), dim3(256), 0, stream, w, a, v);
    hipLaunchKernelGGL(k_s_x16, dim3(4096), dim3(256), 0, stream, x, v, s, x16);
    hipLaunchKernelGGL(k_ygemm, dim3(512), dim3(256), 0, stream, wT, x16, yT);
    hipLaunchKernelGGL(k_fused, dim3(256), dim3(512), 0, stream, mask, s, yT, out);
}